// Round 3
// baseline (115.335 us; speedup 1.0000x reference)
//
#include <hip/hip_runtime.h>
#include <hip/hip_cooperative_groups.h>
#include <math.h>

namespace cg = cooperative_groups;

// Problem constants (from the reference)
#define NBATCH 16384
#define NJOINT 32
#define MIN_TH2 0.25f   // 0.5^2
#define MAX_TH2 4.0f    // 2.0^2

#define BATCHES_PER_BLOCK 16
#define BLOCK 256
#define NBLK (NBATCH / BATCHES_PER_BLOCK)                  // 1024 blocks
#define FLOATS_PER_BLOCK (BATCHES_PER_BLOCK * NJOINT * 3)  // 1536 floats = 6 KB

__global__ void __launch_bounds__(BLOCK) sep_loss_coop(
        const float* __restrict__ kps,
        float* __restrict__ partial,     // d_ws: NBLK floats, fully overwritten each call
        float* __restrict__ out) {
    __shared__ float lds[FLOATS_PER_BLOCK];   // 6 KB
    __shared__ float wsum[BLOCK / 64];

    const int tid = threadIdx.x;
    const int bid = blockIdx.x;
    const long long base = (long long)bid * FLOATS_PER_BLOCK;

    // Coalesced float4 stage: 1536 floats = 384 float4, 256 threads.
    const float4* src4 = (const float4*)(kps + base);
    float4* lds4 = (float4*)lds;
    #pragma unroll
    for (int k = tid; k < FLOATS_PER_BLOCK / 4; k += BLOCK)
        lds4[k] = src4[k];
    __syncthreads();

    // 512 work items (16 batches x 32 joints), 2 per thread.
    float acc = 0.0f;
    #pragma unroll
    for (int s = 0; s < 2; ++s) {
        const int w = s * BLOCK + tid;
        const int b_local = w >> 5;     // 0..15
        const int i       = w & 31;     // 0..31
        const float* jb = &lds[b_local * (NJOINT * 3)];
        const float xi = jb[i * 3 + 0];
        const float yi = jb[i * 3 + 1];
        const float zi = jb[i * 3 + 2];
        #pragma unroll
        for (int j = 0; j < NJOINT; ++j) {
            const float dx = xi - jb[j * 3 + 0];
            const float dy = yi - jb[j * 3 + 1];
            const float dz = zi - jb[j * 3 + 2];
            const float d2 = dx * dx + dy * dy + dz * dz;
            float pen = fmaxf(0.0f, MIN_TH2 - d2) + fmaxf(0.0f, d2 - MAX_TH2);
            if (j == i) pen = 0.0f;     // exclude diagonal
            acc += pen;
        }
    }

    // Wave (64-lane) shuffle reduce, then cross-wave via LDS.
    #pragma unroll
    for (int off = 32; off > 0; off >>= 1)
        acc += __shfl_down(acc, off, 64);
    if ((tid & 63) == 0) wsum[tid >> 6] = acc;
    __syncthreads();

    if (tid == 0)
        partial[bid] = wsum[0] + wsum[1] + wsum[2] + wsum[3];

    // Device-scope visibility of the partial, then grid-wide barrier.
    __threadfence();
    cg::this_grid().sync();

    // Block 0 folds the 1024 partials.
    if (bid == 0) {
        float a = partial[tid] + partial[tid + 256]
                + partial[tid + 512] + partial[tid + 768];
        #pragma unroll
        for (int off = 32; off > 0; off >>= 1)
            a += __shfl_down(a, off, 64);
        if ((tid & 63) == 0) wsum[tid >> 6] = a;
        __syncthreads();
        if (tid == 0) {
            const float total = wsum[0] + wsum[1] + wsum[2] + wsum[3];
            const float mean = total / (float)NBATCH;
            out[0] = powf(mean, 0.4f);
        }
    }
}

extern "C" void kernel_launch(void* const* d_in, const int* in_sizes, int n_in,
                              void* d_out, int out_size, void* d_ws, size_t ws_size,
                              hipStream_t stream) {
    const float* kps = (const float*)d_in[0];
    float* out = (float*)d_out;
    float* partial = (float*)d_ws;   // NBLK floats = 4 KB, overwritten every call

    void* args[] = { (void*)&kps, (void*)&partial, (void*)&out };
    hipLaunchCooperativeKernel((void*)sep_loss_coop, dim3(NBLK), dim3(BLOCK),
                               args, 0, stream);
}

// Round 4
// 27.343 us; speedup vs baseline: 4.2182x; 4.2182x over previous
//
#include <hip/hip_runtime.h>
#include <math.h>

// Problem constants (from the reference)
#define NBATCH 16384
#define NJOINT 32
#define MIN_TH2 0.25f   // 0.5^2
#define MAX_TH2 4.0f    // 2.0^2

#define BATCHES_PER_BLOCK 8
#define BLOCK 256                                  // 8 batches * 32 joints
#define NBLK (NBATCH / BATCHES_PER_BLOCK)          // 2048
#define FLOATS_PER_BLOCK (BATCHES_PER_BLOCK * NJOINT * 3)  // 768
#define FINAL_BID (NBLK - 1)

// Per-block flag sentinel. Distinct per block; can never collide with the
// 0xAAAAAAAA poison pattern or plausible stale garbage for ALL 2048 slots.
#define SENT 0x5EED1000u

// d_ws layout: [ uint32 flags[NBLK] | float partial[NBLK] ]  (16 KB total)

__global__ void __launch_bounds__(BLOCK) sep_loss_onekernel(
        const float* __restrict__ kps,
        unsigned int* __restrict__ flags,
        float* __restrict__ partial,
        float* __restrict__ out) {
    __shared__ float lds[FLOATS_PER_BLOCK];   // 3 KB
    __shared__ float wsum[BLOCK / 64];

    const int tid = threadIdx.x;
    const int bid = blockIdx.x;
    const long long base = (long long)bid * FLOATS_PER_BLOCK;

    // Coalesced float4 stage: 768 floats = 192 float4.
    if (tid < FLOATS_PER_BLOCK / 4)
        ((float4*)lds)[tid] = ((const float4*)(kps + base))[tid];
    __syncthreads();

    const int b_local = tid >> 5;   // 0..7  : batch item within block
    const int i       = tid & 31;   // 0..31 : joint this thread owns
    const float* jb = &lds[b_local * (NJOINT * 3)];

    const float xi = jb[i * 3 + 0];
    const float yi = jb[i * 3 + 1];
    const float zi = jb[i * 3 + 2];

    float acc = 0.0f;
    #pragma unroll
    for (int j = 0; j < NJOINT; ++j) {
        const float dx = xi - jb[j * 3 + 0];
        const float dy = yi - jb[j * 3 + 1];
        const float dz = zi - jb[j * 3 + 2];
        const float d2 = dx * dx + dy * dy + dz * dz;
        float pen = fmaxf(0.0f, MIN_TH2 - d2) + fmaxf(0.0f, d2 - MAX_TH2);
        if (j == i) pen = 0.0f;     // exclude diagonal (d2=0 would add MIN_TH2)
        acc += pen;
    }

    // Wave (64-lane) shuffle reduce + cross-wave LDS fold.
    #pragma unroll
    for (int off = 32; off > 0; off >>= 1)
        acc += __shfl_down(acc, off, 64);
    if ((tid & 63) == 0) wsum[tid >> 6] = acc;
    __syncthreads();

    if (tid == 0) {
        const float block_partial = wsum[0] + wsum[1] + wsum[2] + wsum[3];
        // Publish partial, then release the flag at agent (device) scope so
        // the finalizer block on any XCD sees partial before flag.
        __hip_atomic_store(&partial[bid], block_partial,
                           __ATOMIC_RELAXED, __HIP_MEMORY_SCOPE_AGENT);
        __hip_atomic_store(&flags[bid], SENT ^ (unsigned)bid,
                           __ATOMIC_RELEASE, __HIP_MEMORY_SCOPE_AGENT);
    }

    if (bid != FINAL_BID) return;

    // ---- Finalizer (last block): wait for all flags, fold deterministically.
    float a = 0.0f;
    #pragma unroll
    for (int s = 0; s < NBLK / BLOCK; ++s) {
        const int k = s * BLOCK + tid;
        while (__hip_atomic_load(&flags[k], __ATOMIC_ACQUIRE,
                                 __HIP_MEMORY_SCOPE_AGENT)
               != (SENT ^ (unsigned)k))
            __builtin_amdgcn_s_sleep(4);
        a += __hip_atomic_load(&partial[k], __ATOMIC_RELAXED,
                               __HIP_MEMORY_SCOPE_AGENT);
    }

    #pragma unroll
    for (int off = 32; off > 0; off >>= 1)
        a += __shfl_down(a, off, 64);
    __syncthreads();   // reuse wsum safely after worker phase
    if ((tid & 63) == 0) wsum[tid >> 6] = a;
    __syncthreads();

    if (tid == 0) {
        const float total = wsum[0] + wsum[1] + wsum[2] + wsum[3];
        const float mean = total / (float)NBATCH;
        out[0] = powf(mean, 0.4f);
    }
}

extern "C" void kernel_launch(void* const* d_in, const int* in_sizes, int n_in,
                              void* d_out, int out_size, void* d_ws, size_t ws_size,
                              hipStream_t stream) {
    const float* kps = (const float*)d_in[0];
    float* out = (float*)d_out;
    unsigned int* flags = (unsigned int*)d_ws;             // NBLK u32 = 8 KB
    float* partial = (float*)((char*)d_ws + NBLK * 4);     // NBLK f32 = 8 KB

    sep_loss_onekernel<<<NBLK, BLOCK, 0, stream>>>(kps, flags, partial, out);
}

// Round 5
// 12.783 us; speedup vs baseline: 9.0225x; 2.1389x over previous
//
#include <hip/hip_runtime.h>
#include <math.h>

// Problem constants (from the reference)
#define NBATCH 16384
#define NJOINT 32
#define MIN_TH2 0.25f   // 0.5^2
#define MAX_TH2 4.0f    // 2.0^2

#define BATCHES_PER_BLOCK 16
#define BLOCK 256
#define NBLK (NBATCH / BATCHES_PER_BLOCK)                  // 1024 blocks
#define FLOATS_PER_BLOCK (BATCHES_PER_BLOCK * NJOINT * 3)  // 1536 floats

__global__ void __launch_bounds__(BLOCK) sep_loss_part1(
        const float* __restrict__ kps, float* __restrict__ partial) {
    __shared__ float lds[FLOATS_PER_BLOCK];   // 6 KB
    __shared__ float wsum[BLOCK / 64];

    const int tid = threadIdx.x;
    const int bid = blockIdx.x;
    const long long base = (long long)bid * FLOATS_PER_BLOCK;

    // Coalesced float4 stage: 1536 floats = 384 float4.
    const float4* src4 = (const float4*)(kps + base);
    float4* lds4 = (float4*)lds;
    #pragma unroll
    for (int k = tid; k < FLOATS_PER_BLOCK / 4; k += BLOCK)
        lds4[k] = src4[k];
    __syncthreads();

    // 512 rows (16 batches x 32 joints), 2 per thread.
    float acc = 0.0f;
    #pragma unroll
    for (int s = 0; s < 2; ++s) {
        const int w = s * BLOCK + tid;
        const int b_local = w >> 5;     // 0..15
        const int i       = w & 31;     // 0..31
        const float* jb = &lds[b_local * (NJOINT * 3)];
        const float xi = jb[i * 3 + 0];
        const float yi = jb[i * 3 + 1];
        const float zi = jb[i * 3 + 2];
        #pragma unroll
        for (int j = 0; j < NJOINT; ++j) {
            const float dx = xi - jb[j * 3 + 0];
            const float dy = yi - jb[j * 3 + 1];
            const float dz = zi - jb[j * 3 + 2];
            const float d2 = dx * dx + dy * dy + dz * dz;
            float pen = fmaxf(0.0f, MIN_TH2 - d2) + fmaxf(0.0f, d2 - MAX_TH2);
            if (j == i) pen = 0.0f;     // exclude diagonal
            acc += pen;
        }
    }

    // Wave (64-lane) shuffle reduce, then cross-wave LDS fold.
    #pragma unroll
    for (int off = 32; off > 0; off >>= 1)
        acc += __shfl_down(acc, off, 64);
    if ((tid & 63) == 0) wsum[tid >> 6] = acc;
    __syncthreads();

    if (tid == 0)
        partial[bid] = wsum[0] + wsum[1] + wsum[2] + wsum[3];
}

// Single-wave finalizer: no __syncthreads, no LDS, minimal latency.
__global__ void __launch_bounds__(64) sep_loss_part2(
        const float* __restrict__ partial, float* __restrict__ out) {
    const int lane = threadIdx.x;   // 0..63
    const float4* p4 = (const float4*)partial;   // 1024 floats = 256 float4

    float acc = 0.0f;
    #pragma unroll
    for (int s = 0; s < 4; ++s) {
        const float4 v = p4[lane + 64 * s];
        acc += (v.x + v.y) + (v.z + v.w);
    }

    #pragma unroll
    for (int off = 32; off > 0; off >>= 1)
        acc += __shfl_down(acc, off, 64);

    if (lane == 0) {
        const float mean = acc / (float)NBATCH;
        out[0] = powf(mean, 0.4f);
    }
}

extern "C" void kernel_launch(void* const* d_in, const int* in_sizes, int n_in,
                              void* d_out, int out_size, void* d_ws, size_t ws_size,
                              hipStream_t stream) {
    const float* kps = (const float*)d_in[0];
    float* out = (float*)d_out;
    float* partial = (float*)d_ws;   // NBLK floats = 4 KB, overwritten every call

    sep_loss_part1<<<NBLK, BLOCK, 0, stream>>>(kps, partial);
    sep_loss_part2<<<1, 64, 0, stream>>>(partial, out);
}